// Round 18
// baseline (212.622 us; speedup 1.0000x reference)
//
#include <hip/hip_runtime.h>
#include <math.h>

typedef __bf16 bf16_t;
typedef bf16_t bf16x8 __attribute__((ext_vector_type(8)));
typedef bf16_t bf16x4 __attribute__((ext_vector_type(4)));
typedef float  f32x4  __attribute__((ext_vector_type(4)));

constexpr int H = 64, W = 64, Q = 65536;
constexpr int C = 256, CF = 128;
constexpr int QPB = 32;        // 2 tiles x 16 queries -> 2048 blocks
constexpr int PADC = 264;      // LDS row stride (bf16)

// raw workgroup barrier: orders LDS (lgkmcnt) only; global register-destined
// prefetches (vmcnt) stay in flight across it. All cross-wave deps here are LDS.
#define BAR() asm volatile("s_waitcnt lgkmcnt(0)\n\ts_barrier" ::: "memory")

// ---------------- prep kernels ----------------

__global__ void transpose_cvt_kernel(const float* __restrict__ src, bf16_t* __restrict__ dst, int Crows) {
    __shared__ float tile[32][33];
    int bx = blockIdx.x * 32;
    int by = blockIdx.y * 32;
    int tx = threadIdx.x & 31;
    int ty = threadIdx.x >> 5;
#pragma unroll
    for (int i = 0; i < 4; i++)
        tile[ty + i * 8][tx] = src[(by + ty + i * 8) * 4096 + bx + tx];
    __syncthreads();
#pragma unroll
    for (int i = 0; i < 4; i++)
        dst[(bx + ty + i * 8) * Crows + by + tx] = (bf16_t)tile[tx][ty + i * 8];
}

__global__ void cvt_w_kernel(const float* __restrict__ w1, const float* __restrict__ w2,
                             bf16_t* __restrict__ w1b, bf16_t* __restrict__ w2b) {
    int i = blockIdx.x * 256 + threadIdx.x;
    w1b[i] = (bf16_t)w1[i];
    w2b[i] = (bf16_t)w2[i];
}

__global__ void pack_tab_kernel(const float* __restrict__ wcf, const float* __restrict__ wph,
                                float4* __restrict__ wtab) {
    int k = threadIdx.x;
    float4 v;
    v.x = wcf[k * 2 + 0]; v.y = wcf[k * 2 + 1];
    v.z = wph[k * 2 + 0]; v.w = wph[k * 2 + 1];
    wtab[k] = v;
}

// w3 [3][256] -> w3p [16][256] bf16, rows 3..15 zero
__global__ void cvt_w3_kernel(const float* __restrict__ w3, bf16_t* __restrict__ w3p) {
    int k = threadIdx.x;
#pragma unroll
    for (int n = 0; n < 16; n++)
        w3p[n * 256 + k] = (n < 3) ? (bf16_t)w3[n * 256 + k] : (bf16_t)0.f;
}

// ---------------- main kernel: 2-tile software-pipelined convoy ----------------

// load the wave's 2 W-fragments for k-block kb (W rows = out-cols; A-fragment layout)
#define LOADB(dst, Wptr, kb)                                                                  \
    {                                                                                         \
        dst[0] = *(const bf16x8*)((Wptr) + (wv * 32 + l15) * 256 + (kb) * 32 + l16 * 8);      \
        dst[1] = *(const bf16x8*)((Wptr) + (wv * 32 + 16 + l15) * 256 + (kb) * 32 + l16 * 8); \
    }

// geometry + gather issue for one 64-row tile (8 thr/row, 16 k each)
__device__ __forceinline__ void stage_gather(
    const bf16_t* __restrict__ coefT, const bf16_t* __restrict__ freqT,
    const float* __restrict__ coord, const float* __restrict__ cell,
    int q, int o, int k0,
    bf16x8* fqv, bf16x8* ccv, bf16x8* csv,
    float& rel0, float& rel1, float& rc0, float& rc1, float& area)
{
    const float c0 = coord[q * 2 + 0];
    const float c1 = coord[q * 2 + 1];
    rc0 = cell[q * 2 + 0] * (float)H;
    rc1 = cell[q * 2 + 1] * (float)W;
    const float vx = (o & 2) ? 1.f : -1.f;
    const float vy = (o & 1) ? 1.f : -1.f;
    const float EPS = 1e-6f;
    float g0 = fminf(fmaxf(c0 + vx * (1.f / H) + EPS, -1.f + EPS), 1.f - EPS);
    float g1 = fminf(fmaxf(c1 + vy * (1.f / W) + EPS, -1.f + EPS), 1.f - EPS);
    int iy = (int)floorf(((g0 + 1.f) * (float)H - 1.f) * 0.5f + 0.5f);
    iy = min(max(iy, 0), H - 1);
    int ix = (int)floorf(((g1 + 1.f) * (float)W - 1.f) * 0.5f + 0.5f);
    ix = min(max(ix, 0), W - 1);
    rel0 = (c0 - (-1.f + (2.f * (float)iy + 1.f) / (float)H)) * (float)H;
    rel1 = (c1 - (-1.f + (2.f * (float)ix + 1.f) / (float)W)) * (float)W;
    area = fabsf(rel0 * rel1) + 1e-9f;
    const int pix = iy * W + ix;
    const bf16_t* fq = freqT + pix * CF;
    const bf16_t* cf = coefT + pix * C;
#pragma unroll
    for (int i = 0; i < 2; i++) {
        fqv[i] = *(const bf16x8*)(fq + k0 + i * 8);
        ccv[i] = *(const bf16x8*)(cf + k0 + i * 8);
        csv[i] = *(const bf16x8*)(cf + 128 + k0 + i * 8);
    }
}

// trig + LDS write (consumes gathered regs)
__device__ __forceinline__ void stage_finish(
    const float4* __restrict__ wtab, bf16_t* buf, int row, int k0,
    const bf16x8* fqv, const bf16x8* ccv, const bf16x8* csv,
    float rel0, float rel1, float rc0, float rc1)
{
#pragma unroll
    for (int i = 0; i < 2; i++) {
        bf16x8 vc, vs;
#pragma unroll
        for (int j = 0; j < 8; j++) {
            const int k = k0 + i * 8 + j;
            const float4 tv = wtab[k];
            const float m = (float)fqv[i][j] * (rel0 * tv.x + rel1 * tv.y) + (rc0 * tv.z + rc1 * tv.w);
            const float xr = __builtin_amdgcn_fractf(m * 0.5f);
            vc[j] = (bf16_t)((float)ccv[i][j] * __builtin_amdgcn_cosf(xr));
            vs[j] = (bf16_t)((float)csv[i][j] * __builtin_amdgcn_sinf(xr));
        }
        *(bf16x8*)(buf + row * PADC + k0 + i * 8)       = vc;
        *(bf16x8*)(buf + row * PADC + 128 + k0 + i * 8) = vs;
    }
}

// 64-row swapped-operand MFMA layer (acc[4][2]); queue slots 0,1 preloaded
#define LAYER64(BUF, QUEUE, WPTR, ACC)                                                        \
    {                                                                                         \
        __builtin_amdgcn_s_setprio(1);                                                        \
        _Pragma("unroll")                                                                     \
        for (int kb = 0; kb < 8; kb++) {                                                      \
            if (kb < 6) { LOADB(QUEUE[kb + 2], WPTR, kb + 2); }                               \
            bf16x8 a[4];                                                                      \
            _Pragma("unroll")                                                                 \
            for (int mi = 0; mi < 4; mi++)                                                    \
                a[mi] = *(bf16x8*)((BUF) + (mi * 16 + l15) * PADC + kb * 32 + l16 * 8);       \
            _Pragma("unroll")                                                                 \
            for (int mi = 0; mi < 4; mi++)                                                    \
                _Pragma("unroll")                                                             \
                for (int nf = 0; nf < 2; nf++)                                                \
                    ACC[mi][nf] = __builtin_amdgcn_mfma_f32_16x16x32_bf16(QUEUE[kb][nf], a[mi], ACC[mi][nf], 0, 0, 0); \
        }                                                                                     \
        __builtin_amdgcn_s_setprio(0);                                                        \
    }

#define ZEROACC(ACC)                                                                          \
    _Pragma("unroll")                                                                         \
    for (int mi = 0; mi < 4; mi++)                                                            \
        _Pragma("unroll")                                                                     \
        for (int nf = 0; nf < 2; nf++) {                                                      \
            f32x4 z = {0.f, 0.f, 0.f, 0.f};                                                   \
            ACC[mi][nf] = z;                                                                  \
        }

// relu+bias writeback: lane holds row = mi*16+l15, cols colb..colb+3 -> b64 stores
#define WRITEBACK64(BUF, BIAS, ACC)                                                           \
    _Pragma("unroll")                                                                         \
    for (int nf = 0; nf < 2; nf++) {                                                          \
        const int colb = wv * 32 + nf * 16 + l16 * 4;                                         \
        const float4 bv = *(const float4*)((BIAS) + colb);                                    \
        _Pragma("unroll")                                                                     \
        for (int mi = 0; mi < 4; mi++) {                                                      \
            const int row_ = mi * 16 + l15;                                                   \
            bf16x4 hh;                                                                        \
            hh[0] = (bf16_t)fmaxf(ACC[mi][nf][0] + bv.x, 0.f);                                \
            hh[1] = (bf16_t)fmaxf(ACC[mi][nf][1] + bv.y, 0.f);                                \
            hh[2] = (bf16_t)fmaxf(ACC[mi][nf][2] + bv.z, 0.f);                                \
            hh[3] = (bf16_t)fmaxf(ACC[mi][nf][3] + bv.w, 0.f);                                \
            *(bf16x4*)((BUF) + row_ * PADC + colb) = hh;                                      \
        }                                                                                     \
    }

// layer-3 on waves 0..3 (tile rows wv*16..); PBASE = global preds row offset
#define L3TILE(BUF, PBASE)                                                                    \
    if (wv < 4) {                                                                             \
        f32x4 acc3 = {0.f, 0.f, 0.f, 0.f};                                                    \
        _Pragma("unroll")                                                                     \
        for (int kb = 0; kb < 8; kb++) {                                                      \
            bf16x8 a = *(bf16x8*)((BUF) + (wv * 16 + l15) * PADC + kb * 32 + l16 * 8);        \
            bf16x8 b = *(const bf16x8*)(w3p + l15 * 256 + kb * 32 + l16 * 8);                 \
            acc3 = __builtin_amdgcn_mfma_f32_16x16x32_bf16(a, b, acc3, 0, 0, 0);              \
        }                                                                                     \
        if (l15 < 3) {                                                                        \
            const float bv = b3[l15];                                                         \
            _Pragma("unroll")                                                                 \
            for (int r = 0; r < 4; r++)                                                       \
                predsS[((PBASE) + wv * 16 + l16 * 4 + r) * 3 + l15] = acc3[r] + bv;           \
        }                                                                                     \
    }

// combine 16 queries x 3 channels; QBASE = first query, RBASE = preds/area row offset
#define COMBINE(QBASE, RBASE)                                                                 \
    if (t < 48) {                                                                             \
        const int ch = t >> 4;                                                                \
        const int qL = t & 15;                                                                \
        const int q_ = (QBASE) + qL;                                                          \
        const int r0 = (RBASE) + qL * 4;                                                      \
        const float a0 = areaS[r0 + 0], a1 = areaS[r0 + 1];                                   \
        const float a2 = areaS[r0 + 2], a3 = areaS[r0 + 3];                                   \
        const float inv = 1.f / (a0 + a1 + a2 + a3);                                          \
        const float ret = predsS[(r0 + 0) * 3 + ch] * a3 * inv                                \
                        + predsS[(r0 + 1) * 3 + ch] * a2 * inv                                \
                        + predsS[(r0 + 2) * 3 + ch] * a1 * inv                                \
                        + predsS[(r0 + 3) * 3 + ch] * a0 * inv;                               \
        const float c0 = coord[q_ * 2 + 0];                                                   \
        const float c1 = coord[q_ * 2 + 1];                                                   \
        float gy = fminf(fmaxf(((c0 + 1.f) * (float)H - 1.f) * 0.5f, 0.f), (float)(H - 1));   \
        float gx = fminf(fmaxf(((c1 + 1.f) * (float)W - 1.f) * 0.5f, 0.f), (float)(W - 1));   \
        int y0 = (int)floorf(gy); int x0 = (int)floorf(gx);                                   \
        int y1 = min(y0 + 1, H - 1); int x1 = min(x0 + 1, W - 1);                             \
        const float wy = gy - (float)y0, wx = gx - (float)x0;                                 \
        const float* ip = img + ch * 4096;                                                    \
        const float samp = ip[y0 * 64 + x0] * (1.f - wy) * (1.f - wx)                         \
                         + ip[y0 * 64 + x1] * (1.f - wy) * wx                                 \
                         + ip[y1 * 64 + x0] * wy * (1.f - wx)                                 \
                         + ip[y1 * 64 + x1] * wy * wx;                                        \
        out[q_ * 3 + ch] = ret + samp;                                                        \
    }

__global__ __launch_bounds__(512, 4)
void lte_fused_kernel(const bf16_t* __restrict__ coefT,  // [4096][256] bf16
                      const bf16_t* __restrict__ freqT,  // [4096][128] bf16
                      const bf16_t* __restrict__ w1b,    // [256][256] (out,in)
                      const bf16_t* __restrict__ w2b,
                      const bf16_t* __restrict__ w3p,    // [16][256] padded bf16
                      const float4* __restrict__ wtab,   // [128]
                      const float* __restrict__ img,     // [3][64][64]
                      const float* __restrict__ coord,   // [Q][2]
                      const float* __restrict__ cell,    // [Q][2]
                      const float* __restrict__ b1,
                      const float* __restrict__ b2,
                      const float* __restrict__ b3,
                      float* __restrict__ out)           // [Q][3]
{
    extern __shared__ char smem[];
    bf16_t* bufA   = (bf16_t*)smem;              // [64][264] (33792 B)
    bf16_t* bufB   = (bf16_t*)(smem + 33792);    // [64][264]
    float*  areaS  = (float*)(smem + 67584);     // [128] (A:0-63, B:64-127)
    float*  predsS = (float*)(smem + 68096);     // [128][3]

    const int t    = threadIdx.x;
    const int lane = t & 63;
    const int wv   = t >> 6;     // wave 0..7 -> 32-col stripe
    const int l15  = lane & 15;
    const int l16  = lane >> 4;
    // stage mapping: 8 thr/row over 64 rows
    const int row  = t >> 3;     // 0..63
    const int t8   = t & 7;
    const int k0   = t8 * 16;
    const int o    = row & 3;
    const int qrow = row >> 2;   // 0..15

    const int qA = blockIdx.x * QPB;       // tile A: queries qA..qA+15
    const int qB = qA + 16;                // tile B

    // W1 queue prefetch at entry (hides under stage A)
    bf16x8 bq1[8][2], bq2[8][2];
    LOADB(bq1[0], w1b, 0);
    LOADB(bq1[1], w1b, 1);

    // ---- stage tile A (fully exposed: pipeline prologue) ----
    {
        bf16x8 fqv[2], ccv[2], csv[2];
        float rel0, rel1, rc0, rc1, area;
        stage_gather(coefT, freqT, coord, cell, qA + qrow, o, k0, fqv, ccv, csv, rel0, rel1, rc0, rc1, area);
        if (t8 == 0) areaS[row] = area;
        stage_finish(wtab, bufA, row, k0, fqv, ccv, csv, rel0, rel1, rc0, rc1);
    }
    BAR();  // X(A) visible

    // ---- phase: L1(A) with stage(B) hidden under it ----
    bf16x8 fqB[2], ccB[2], csB[2];
    float rel0B, rel1B, rc0B, rc1B, areaB;
    stage_gather(coefT, freqT, coord, cell, qB + qrow, o, k0, fqB, ccB, csB, rel0B, rel1B, rc0B, rc1B, areaB);
    if (t8 == 0) areaS[64 + row] = areaB;

    f32x4 acc[4][2];
    ZEROACC(acc);
    LAYER64(bufA, bq1, w1b, acc);          // B-gather latency hides under these MFMAs
    LOADB(bq2[0], w2b, 0);                 // W2 queue for A
    LOADB(bq2[1], w2b, 1);
    stage_finish(wtab, bufB, row, k0, fqB, ccB, csB, rel0B, rel1B, rc0B, rc1B);
    BAR();  // bufA reads done; X(B) written
    WRITEBACK64(bufA, b1, acc);            // h1(A)
    BAR();

    // ---- phase: L2(A); prefetch W1 queue for B ----
    ZEROACC(acc);
    LAYER64(bufA, bq2, w2b, acc);
    LOADB(bq1[0], w1b, 0);
    LOADB(bq1[1], w1b, 1);
    BAR();  // bufA h1 reads done
    WRITEBACK64(bufA, b2, acc);            // h2(A)
    BAR();

    // ---- phase: L3(A) merged with L1(B) ----
    L3TILE(bufA, 0);
    ZEROACC(acc);
    LAYER64(bufB, bq1, w1b, acc);
    LOADB(bq2[0], w2b, 0);
    LOADB(bq2[1], w2b, 1);
    BAR();  // bufB reads done; preds(A) written
    WRITEBACK64(bufB, b1, acc);            // h1(B)
    COMBINE(qA, 0);                        // combine A overlaps h1(B) writeback
    BAR();

    // ---- phase: L2(B) ----
    ZEROACC(acc);
    LAYER64(bufB, bq2, w2b, acc);
    BAR();
    WRITEBACK64(bufB, b2, acc);            // h2(B)
    BAR();

    // ---- L3(B) + combine(B) ----
    L3TILE(bufB, 64);
    BAR();
    COMBINE(qB, 64);
}

// ---------------- launch ----------------

extern "C" void kernel_launch(void* const* d_in, const int* in_sizes, int n_in,
                              void* d_out, int out_size, void* d_ws, size_t ws_size,
                              hipStream_t stream) {
    const float* img   = (const float*)d_in[0];
    const float* coef  = (const float*)d_in[1];
    const float* freq  = (const float*)d_in[2];
    const float* coord = (const float*)d_in[3];
    const float* cell  = (const float*)d_in[4];
    const float* wcf   = (const float*)d_in[5];
    const float* wph   = (const float*)d_in[6];
    const float* w1    = (const float*)d_in[7];
    const float* b1    = (const float*)d_in[8];
    const float* w2    = (const float*)d_in[9];
    const float* b2    = (const float*)d_in[10];
    const float* w3    = (const float*)d_in[11];
    const float* b3    = (const float*)d_in[12];
    float* out = (float*)d_out;

    char* ws = (char*)d_ws;
    bf16_t* coefT = (bf16_t*)ws;                  // 2,097,152
    bf16_t* freqT = (bf16_t*)(ws + 2097152);      // 1,048,576
    bf16_t* w1b   = (bf16_t*)(ws + 3145728);      // 131,072
    bf16_t* w2b   = (bf16_t*)(ws + 3276800);      // 131,072
    float4* wtab  = (float4*)(ws + 3407872);      // 2,048
    bf16_t* w3p   = (bf16_t*)(ws + 3409920);      // 8,192

    transpose_cvt_kernel<<<dim3(128, 8), 256, 0, stream>>>(coef, coefT, 256);
    transpose_cvt_kernel<<<dim3(128, 4), 256, 0, stream>>>(freq, freqT, 128);
    cvt_w_kernel<<<256, 256, 0, stream>>>(w1, w2, w1b, w2b);
    pack_tab_kernel<<<1, 128, 0, stream>>>(wcf, wph, wtab);
    cvt_w3_kernel<<<1, 256, 0, stream>>>(w3, w3p);

    const size_t ldsBytes = 69632;  // 2x33792 buf + 512 area + 1536 preds
    lte_fused_kernel<<<Q / QPB, 512, ldsBytes, stream>>>(
        coefT, freqT, w1b, w2b, w3p, wtab, img, coord, cell, b1, b2, b3, out);
}

// Round 19
// 166.579 us; speedup vs baseline: 1.2764x; 1.2764x over previous
//
#include <hip/hip_runtime.h>
#include <math.h>

typedef __bf16 bf16_t;
typedef bf16_t bf16x8 __attribute__((ext_vector_type(8)));
typedef bf16_t bf16x4 __attribute__((ext_vector_type(4)));
typedef float  f32x4  __attribute__((ext_vector_type(4)));

constexpr int H = 64, W = 64, Q = 65536;
constexpr int C = 256, CF = 128;
constexpr int QPB = 32;        // queries per block -> 2048 blocks
constexpr int PADC = 264;      // LDS row stride (bf16)

// raw workgroup barrier: orders LDS (lgkmcnt) only; global register-destined
// prefetches (vmcnt) stay in flight across it. All cross-wave deps here are LDS.
#define BAR() asm volatile("s_waitcnt lgkmcnt(0)\n\ts_barrier" ::: "memory")

// ---------------- prep kernels ----------------

// src [Crows][4096] f32 -> dst [4096][Crows] bf16
__global__ void transpose_cvt_kernel(const float* __restrict__ src, bf16_t* __restrict__ dst, int Crows) {
    __shared__ float tile[32][33];
    int bx = blockIdx.x * 32;
    int by = blockIdx.y * 32;
    int tx = threadIdx.x & 31;
    int ty = threadIdx.x >> 5;
#pragma unroll
    for (int i = 0; i < 4; i++)
        tile[ty + i * 8][tx] = src[(by + ty + i * 8) * 4096 + bx + tx];
    __syncthreads();
#pragma unroll
    for (int i = 0; i < 4; i++)
        dst[(bx + ty + i * 8) * Crows + by + tx] = (bf16_t)tile[tx][ty + i * 8];
}

__global__ void cvt_w_kernel(const float* __restrict__ w1, const float* __restrict__ w2,
                             bf16_t* __restrict__ w1b, bf16_t* __restrict__ w2b) {
    int i = blockIdx.x * 256 + threadIdx.x;
    w1b[i] = (bf16_t)w1[i];
    w2b[i] = (bf16_t)w2[i];
}

__global__ void pack_tab_kernel(const float* __restrict__ wcf, const float* __restrict__ wph,
                                float4* __restrict__ wtab) {
    int k = threadIdx.x;
    float4 v;
    v.x = wcf[k * 2 + 0]; v.y = wcf[k * 2 + 1];
    v.z = wph[k * 2 + 0]; v.w = wph[k * 2 + 1];
    wtab[k] = v;
}

// w3 [3][256] -> w3p [16][256] bf16, rows 3..15 zero
__global__ void cvt_w3_kernel(const float* __restrict__ w3, bf16_t* __restrict__ w3p) {
    int k = threadIdx.x;
#pragma unroll
    for (int n = 0; n < 16; n++)
        w3p[n * 256 + k] = (n < 3) ? (bf16_t)w3[n * 256 + k] : (bf16_t)0.f;
}

// ---------------- fused main kernel (champion: R13 + entry-prefetch + setprio) ----------------

// load the wave's 2 W-fragments for k-block kb (W rows = out-cols; A-fragment layout)
#define LOADB(dst, Wptr, kb)                                                                  \
    {                                                                                         \
        dst[0] = *(const bf16x8*)((Wptr) + (wv * 32 + l15) * 256 + (kb) * 32 + l16 * 8);      \
        dst[1] = *(const bf16x8*)((Wptr) + (wv * 32 + 16 + l15) * 256 + (kb) * 32 + l16 * 8); \
    }

__global__ __launch_bounds__(512, 4)
void lte_fused_kernel(const bf16_t* __restrict__ coefT,  // [4096][256] bf16
                      const bf16_t* __restrict__ freqT,  // [4096][128] bf16
                      const bf16_t* __restrict__ w1b,    // [256][256] (out,in)
                      const bf16_t* __restrict__ w2b,
                      const bf16_t* __restrict__ w3p,    // [16][256] padded bf16
                      const float4* __restrict__ wtab,   // [128] packed (wcf0,wcf1,wph0,wph1)
                      const float* __restrict__ img,     // [3][64][64]
                      const float* __restrict__ coord,   // [Q][2]
                      const float* __restrict__ cell,    // [Q][2]
                      const float* __restrict__ b1,
                      const float* __restrict__ b2,
                      const float* __restrict__ b3,
                      float* __restrict__ out)           // [Q][3]
{
    extern __shared__ char smem[];
    bf16_t* buf    = (bf16_t*)smem;              // [128][264] bf16: X -> h1 -> h2 (67584 B)
    float*  areaS  = (float*)(smem + 67584);     // [128]
    float*  predsS = (float*)(smem + 68096);     // [128][3]

    const int t    = threadIdx.x;
    const int lane = t & 63;
    const int wv   = t >> 6;     // wave id 0..7 -> 32-col stripe
    const int l15  = lane & 15;
    const int l16  = lane >> 4;

    // issue layer-1 W prefetch at kernel ENTRY — latency hides under stage-1 trig
    bf16x8 b1q[8][2];
    LOADB(b1q[0], w1b, 0);
    LOADB(b1q[1], w1b, 1);

    // ---- stage 1: features -> X (bf16) in LDS. 4 threads/row, 32 k each ----
    {
        const int row = t >> 2;   // 0..127
        const int t4  = t & 3;
        const int qL  = row >> 2;
        const int o   = row & 3;
        const int q   = blockIdx.x * QPB + qL;
        const float c0  = coord[q * 2 + 0];
        const float c1  = coord[q * 2 + 1];
        const float rc0 = cell[q * 2 + 0] * (float)H;
        const float rc1 = cell[q * 2 + 1] * (float)W;
        const float vx = (o & 2) ? 1.f : -1.f;
        const float vy = (o & 1) ? 1.f : -1.f;
        const float EPS = 1e-6f;
        float g0 = fminf(fmaxf(c0 + vx * (1.f / H) + EPS, -1.f + EPS), 1.f - EPS);
        float g1 = fminf(fmaxf(c1 + vy * (1.f / W) + EPS, -1.f + EPS), 1.f - EPS);
        int iy = (int)floorf(((g0 + 1.f) * (float)H - 1.f) * 0.5f + 0.5f);
        iy = min(max(iy, 0), H - 1);
        int ix = (int)floorf(((g1 + 1.f) * (float)W - 1.f) * 0.5f + 0.5f);
        ix = min(max(ix, 0), W - 1);
        const float rel0 = (c0 - (-1.f + (2.f * (float)iy + 1.f) / (float)H)) * (float)H;
        const float rel1 = (c1 - (-1.f + (2.f * (float)ix + 1.f) / (float)W)) * (float)W;
        if (t4 == 0) areaS[row] = fabsf(rel0 * rel1) + 1e-9f;
        const int pix = iy * W + ix;
        const bf16_t* fq = freqT + pix * CF;
        const bf16_t* cf = coefT + pix * C;
        const int k0 = t4 * 32;

        // issue ALL gathers up front (12 x 16B)
        bf16x8 fqv[4], ccv[4], csv[4];
#pragma unroll
        for (int i = 0; i < 4; i++) {
            fqv[i] = *(const bf16x8*)(fq + k0 + i * 8);
            ccv[i] = *(const bf16x8*)(cf + k0 + i * 8);
            csv[i] = *(const bf16x8*)(cf + 128 + k0 + i * 8);
        }
#pragma unroll
        for (int i = 0; i < 4; i++) {
            bf16x8 vc, vs;
#pragma unroll
            for (int j = 0; j < 8; j++) {
                const int k = k0 + i * 8 + j;
                const float4 tv = wtab[k];
                const float proj = rel0 * tv.x + rel1 * tv.y;
                const float ph   = rc0 * tv.z + rc1 * tv.w;
                const float m = (float)fqv[i][j] * proj + ph;
                // sin(pi*m) = sin(2*pi*fract(m/2)) -- native HW trig
                const float xr  = __builtin_amdgcn_fractf(m * 0.5f);
                const float s   = __builtin_amdgcn_sinf(xr);
                const float cst = __builtin_amdgcn_cosf(xr);
                vc[j] = (bf16_t)((float)ccv[i][j] * cst);
                vs[j] = (bf16_t)((float)csv[i][j] * s);
            }
            *(bf16x8*)(buf + row * PADC + k0 + i * 8)       = vc;
            *(bf16x8*)(buf + row * PADC + 128 + k0 + i * 8) = vs;
        }
    }

    BAR();

    // ---- layer 1: swapped-operand MFMA: D = W_frag * X_frag (transposed C).
    //      Lane holds row = mi*16+l15, cols = wv*32+nf*16+l16*4..+3 -> b64 stores.
    bf16x8 b2q[8][2];
    {
        f32x4 acc[8][2];
#pragma unroll
        for (int mi = 0; mi < 8; mi++)
#pragma unroll
            for (int nf = 0; nf < 2; nf++) {
                f32x4 z = {0.f, 0.f, 0.f, 0.f};
                acc[mi][nf] = z;
            }
        __builtin_amdgcn_s_setprio(1);
#pragma unroll
        for (int kb = 0; kb < 8; kb++) {
            if (kb < 6) { LOADB(b1q[kb + 2], w1b, kb + 2); }
            bf16x8 a[8];
#pragma unroll
            for (int mi = 0; mi < 8; mi++)
                a[mi] = *(bf16x8*)(buf + (mi * 16 + l15) * PADC + kb * 32 + l16 * 8);
#pragma unroll
            for (int mi = 0; mi < 8; mi++)
#pragma unroll
                for (int nf = 0; nf < 2; nf++)
                    acc[mi][nf] = __builtin_amdgcn_mfma_f32_16x16x32_bf16(b1q[kb][nf], a[mi], acc[mi][nf], 0, 0, 0);
        }
        __builtin_amdgcn_s_setprio(0);
        // prefetch layer-2 kb=0,1 -- survives both raw barriers below
        LOADB(b2q[0], w2b, 0);
        LOADB(b2q[1], w2b, 1);
        BAR();  // all reads of X done
#pragma unroll
        for (int nf = 0; nf < 2; nf++) {
            const int colb = wv * 32 + nf * 16 + l16 * 4;
            const float4 bv = *(const float4*)(b1 + colb);
#pragma unroll
            for (int mi = 0; mi < 8; mi++) {
                const int row = mi * 16 + l15;
                bf16x4 h;
                h[0] = (bf16_t)fmaxf(acc[mi][nf][0] + bv.x, 0.f);
                h[1] = (bf16_t)fmaxf(acc[mi][nf][1] + bv.y, 0.f);
                h[2] = (bf16_t)fmaxf(acc[mi][nf][2] + bv.z, 0.f);
                h[3] = (bf16_t)fmaxf(acc[mi][nf][3] + bv.w, 0.f);
                *(bf16x4*)(buf + row * PADC + colb) = h;
            }
        }
        BAR();  // h1 visible
    }

    // ---- layer 2 (same swapped-operand scheme) ----
    {
        f32x4 acc[8][2];
#pragma unroll
        for (int mi = 0; mi < 8; mi++)
#pragma unroll
            for (int nf = 0; nf < 2; nf++) {
                f32x4 z = {0.f, 0.f, 0.f, 0.f};
                acc[mi][nf] = z;
            }
        __builtin_amdgcn_s_setprio(1);
#pragma unroll
        for (int kb = 0; kb < 8; kb++) {
            if (kb < 6) { LOADB(b2q[kb + 2], w2b, kb + 2); }
            bf16x8 a[8];
#pragma unroll
            for (int mi = 0; mi < 8; mi++)
                a[mi] = *(bf16x8*)(buf + (mi * 16 + l15) * PADC + kb * 32 + l16 * 8);
#pragma unroll
            for (int mi = 0; mi < 8; mi++)
#pragma unroll
                for (int nf = 0; nf < 2; nf++)
                    acc[mi][nf] = __builtin_amdgcn_mfma_f32_16x16x32_bf16(b2q[kb][nf], a[mi], acc[mi][nf], 0, 0, 0);
        }
        __builtin_amdgcn_s_setprio(0);
        BAR();  // all reads of h1 done
#pragma unroll
        for (int nf = 0; nf < 2; nf++) {
            const int colb = wv * 32 + nf * 16 + l16 * 4;
            const float4 bv = *(const float4*)(b2 + colb);
#pragma unroll
            for (int mi = 0; mi < 8; mi++) {
                const int row = mi * 16 + l15;
                bf16x4 h;
                h[0] = (bf16_t)fmaxf(acc[mi][nf][0] + bv.x, 0.f);
                h[1] = (bf16_t)fmaxf(acc[mi][nf][1] + bv.y, 0.f);
                h[2] = (bf16_t)fmaxf(acc[mi][nf][2] + bv.z, 0.f);
                h[3] = (bf16_t)fmaxf(acc[mi][nf][3] + bv.w, 0.f);
                *(bf16x4*)(buf + row * PADC + colb) = h;
            }
        }
        BAR();  // h2 visible
    }

    // ---- layer 3: MFMA vs padded w3 (conflict-free). wave wv = rows wv*16.. ----
    {
        f32x4 acc3 = {0.f, 0.f, 0.f, 0.f};
        __builtin_amdgcn_s_setprio(1);
#pragma unroll
        for (int kb = 0; kb < 8; kb++) {
            bf16x8 a = *(bf16x8*)(buf + (wv * 16 + l15) * PADC + kb * 32 + l16 * 8);
            bf16x8 b = *(const bf16x8*)(w3p + l15 * 256 + kb * 32 + l16 * 8);
            acc3 = __builtin_amdgcn_mfma_f32_16x16x32_bf16(a, b, acc3, 0, 0, 0);
        }
        __builtin_amdgcn_s_setprio(0);
        if (l15 < 3) {
            const float bv = b3[l15];
#pragma unroll
            for (int r = 0; r < 4; r++) {
                const int row = wv * 16 + l16 * 4 + r;
                predsS[row * 3 + l15] = acc3[r] + bv;
            }
        }
    }
    BAR();  // preds visible

    // ---- combine: area weights (reversed) + bilinear border sample ----
    if (t < QPB) {
        const int qL = t;
        const int q  = blockIdx.x * QPB + qL;
        const int r0 = qL * 4;
        const float a0 = areaS[r0 + 0], a1 = areaS[r0 + 1], a2 = areaS[r0 + 2], a3 = areaS[r0 + 3];
        const float inv = 1.f / (a0 + a1 + a2 + a3);
        const float wgt0 = a3 * inv, wgt1 = a2 * inv, wgt2 = a1 * inv, wgt3 = a0 * inv;
        const float c0 = coord[q * 2 + 0];
        const float c1 = coord[q * 2 + 1];
        float gy = fminf(fmaxf(((c0 + 1.f) * (float)H - 1.f) * 0.5f, 0.f), (float)(H - 1));
        float gx = fminf(fmaxf(((c1 + 1.f) * (float)W - 1.f) * 0.5f, 0.f), (float)(W - 1));
        int y0 = (int)floorf(gy); int x0 = (int)floorf(gx);
        int y1 = min(y0 + 1, H - 1); int x1 = min(x0 + 1, W - 1);
        const float wy = gy - (float)y0, wx = gx - (float)x0;
#pragma unroll
        for (int ch = 0; ch < 3; ch++) {
            const float ret = predsS[(r0 + 0) * 3 + ch] * wgt0 + predsS[(r0 + 1) * 3 + ch] * wgt1
                            + predsS[(r0 + 2) * 3 + ch] * wgt2 + predsS[(r0 + 3) * 3 + ch] * wgt3;
            const float* ip = img + ch * 4096;
            const float v00 = ip[y0 * 64 + x0], v01 = ip[y0 * 64 + x1];
            const float v10 = ip[y1 * 64 + x0], v11 = ip[y1 * 64 + x1];
            const float samp = v00 * (1.f - wy) * (1.f - wx) + v01 * (1.f - wy) * wx
                             + v10 * wy * (1.f - wx) + v11 * wy * wx;
            out[q * 3 + ch] = ret + samp;
        }
    }
}

// ---------------- launch ----------------

extern "C" void kernel_launch(void* const* d_in, const int* in_sizes, int n_in,
                              void* d_out, int out_size, void* d_ws, size_t ws_size,
                              hipStream_t stream) {
    const float* img   = (const float*)d_in[0];
    const float* coef  = (const float*)d_in[1];
    const float* freq  = (const float*)d_in[2];
    const float* coord = (const float*)d_in[3];
    const float* cell  = (const float*)d_in[4];
    const float* wcf   = (const float*)d_in[5];
    const float* wph   = (const float*)d_in[6];
    const float* w1    = (const float*)d_in[7];
    const float* b1    = (const float*)d_in[8];
    const float* w2    = (const float*)d_in[9];
    const float* b2    = (const float*)d_in[10];
    const float* w3    = (const float*)d_in[11];
    const float* b3    = (const float*)d_in[12];
    float* out = (float*)d_out;

    char* ws = (char*)d_ws;
    bf16_t* coefT = (bf16_t*)ws;                  // 2,097,152
    bf16_t* freqT = (bf16_t*)(ws + 2097152);      // 1,048,576
    bf16_t* w1b   = (bf16_t*)(ws + 3145728);      // 131,072
    bf16_t* w2b   = (bf16_t*)(ws + 3276800);      // 131,072
    float4* wtab  = (float4*)(ws + 3407872);      // 2,048
    bf16_t* w3p   = (bf16_t*)(ws + 3409920);      // 8,192

    transpose_cvt_kernel<<<dim3(128, 8), 256, 0, stream>>>(coef, coefT, 256);
    transpose_cvt_kernel<<<dim3(128, 4), 256, 0, stream>>>(freq, freqT, 128);
    cvt_w_kernel<<<256, 256, 0, stream>>>(w1, w2, w1b, w2b);
    pack_tab_kernel<<<1, 128, 0, stream>>>(wcf, wph, wtab);
    cvt_w3_kernel<<<1, 256, 0, stream>>>(w3, w3p);

    const size_t ldsBytes = 69632;  // 67584 buf + 512 area + 1536 preds
    lte_fused_kernel<<<Q / QPB, 512, ldsBytes, stream>>>(
        coefT, freqT, w1b, w2b, w3p, wtab, img, coord, cell, b1, b2, b3, out);
}